// Round 19
// baseline (117.334 us; speedup 1.0000x reference)
//
#include <hip/hip_runtime.h>
#include <math.h>

#define B_N 256
#define V_N 6890
#define J_N 24
#define KPF 207
#define KE  218
#define NCOL (V_N*3)   // 20670

typedef float v2f __attribute__((ext_vector_type(2)));

__device__ __constant__ int c_par[24] = {-1,0,0,0,1,2,3,4,5,6,7,8,9,9,9,12,13,14,16,17,18,19,20,21};

// ws layout (floats)
#define WS_PF   0
#define WS_A    (WS_PF + B_N*KE)                 // 55808 (PF stored transposed [KE][B_N])
#define WS_EXT  (WS_A + B_N*J_N*12)              // 129536
#define WS_PART (WS_EXT + 11*NCOL)               // 356906 (96*33 = 3168)

// ---------------- stage 0: merged {joint-regressor partials | EXT build} ----------------
__global__ __launch_bounds__(256) void k_pre(const float* __restrict__ Jreg,
        const float* __restrict__ vt, const float* __restrict__ sd,
        float* __restrict__ part, float* __restrict__ EXT)
{
    int bid = blockIdx.x;
    int tid = threadIdx.x;
    __shared__ float red[4][33];

    if (bid < 96) {
        int j = bid >> 2;
        int c = bid & 3;
        int v0 = c * 1723;
        int v1 = v0 + 1723; if (v1 > V_N) v1 = V_N;

        float acc[33];
        #pragma unroll
        for (int i = 0; i < 33; ++i) acc[i] = 0.f;

        for (int v = v0 + tid; v < v1; v += 256) {
            float r = Jreg[j*V_N + v];
            const float* s = sd + v*30;
            #pragma unroll
            for (int i = 0; i < 30; ++i) acc[i] += r * s[i];
            #pragma unroll
            for (int k = 0; k < 3; ++k) acc[30+k] += r * vt[v*3+k];
        }
        #pragma unroll
        for (int i = 0; i < 33; ++i) {
            #pragma unroll
            for (int off = 32; off > 0; off >>= 1)
                acc[i] += __shfl_down(acc[i], off, 64);
        }
        int wave = tid >> 6, lane = tid & 63;
        if (lane == 0) {
            #pragma unroll
            for (int i = 0; i < 33; ++i) red[wave][i] = acc[i];
        }
        __syncthreads();
        if (tid < 33) {
            float s = red[0][tid] + red[1][tid] + red[2][tid] + red[3][tid];
            part[(j*4 + c)*33 + tid] = s;
        }
    } else {
        int idx = (bid - 96)*256 + tid;
        if (idx < NCOL) {
            int v = idx / 3, k = idx - v*3;
            #pragma unroll
            for (int l = 0; l < 10; ++l) EXT[l*NCOL + idx] = sd[v*30 + k*10 + l];
            EXT[10*NCOL + idx] = vt[idx];
        }
    }
}

// ---------------- stage 1: per-batch Rodrigues + kinematic chain (+ folded jred) ----------------
// PF is written TRANSPOSED: PFt[r*B_N + b]
__global__ __launch_bounds__(64) void k_batch(const float* __restrict__ pose,
        const float* __restrict__ betas, const float* __restrict__ part,
        float* __restrict__ PFt, float* __restrict__ A, float* __restrict__ outJ)
{
    int b = blockIdx.x;
    int lane = threadIdx.x;
    __shared__ float sR[24][9];
    __shared__ float sJ[24][3];
    __shared__ float sG[24][12];

    if (lane < 24) {
        float R[9];
        if (lane < 22) {
            float p0 = pose[b*72 + lane*3 + 0];
            float p1 = pose[b*72 + lane*3 + 1];
            float p2 = pose[b*72 + lane*3 + 2];
            float a0 = p0 + 1e-8f, a1 = p1 + 1e-8f, a2 = p2 + 1e-8f;
            float angle = sqrtf(a0*a0 + a1*a1 + a2*a2);
            float inv = 1.f / angle;
            float rx = p0*inv, ry = p1*inv, rz = p2*inv;
            float cc = cosf(angle), ss = sinf(angle), ic = 1.f - cc;
            R[0] = 1.f - ic*(ry*ry + rz*rz);
            R[1] = -ss*rz + ic*rx*ry;
            R[2] =  ss*ry + ic*rx*rz;
            R[3] =  ss*rz + ic*rx*ry;
            R[4] = 1.f - ic*(rx*rx + rz*rz);
            R[5] = -ss*rx + ic*ry*rz;
            R[6] = -ss*ry + ic*rx*rz;
            R[7] =  ss*rx + ic*ry*rz;
            R[8] = 1.f - ic*(rx*rx + ry*ry);
        } else {
            R[0]=1.f;R[1]=0.f;R[2]=0.f;R[3]=0.f;R[4]=1.f;R[5]=0.f;R[6]=0.f;R[7]=0.f;R[8]=1.f;
        }
        #pragma unroll
        for (int e = 0; e < 9; ++e) sR[lane][e] = R[e];
    }
    __syncthreads();
    for (int idx = lane; idx < 72; idx += 64) {
        int j = idx / 3, k = idx - j*3;
        const float* p0 = part + (j*4 + 0)*33;
        const float* p1 = part + (j*4 + 1)*33;
        const float* p2 = part + (j*4 + 2)*33;
        const float* p3 = part + (j*4 + 3)*33;
        float s = p0[30+k] + p1[30+k] + p2[30+k] + p3[30+k];
        #pragma unroll
        for (int l = 0; l < 10; ++l) {
            float js = p0[k*10+l] + p1[k*10+l] + p2[k*10+l] + p3[k*10+l];
            s += betas[b*10+l] * js;
        }
        sJ[j][k] = s;
    }
    __syncthreads();
    for (int idx = lane; idx < KPF; idx += 64) {
        int jj = 1 + idx/9, e = idx - (idx/9)*9;
        float id = (e==0 || e==4 || e==8) ? 1.f : 0.f;
        PFt[idx*B_N + b] = sR[jj][e] - id;
    }
    if (lane < 10) PFt[(KPF+lane)*B_N + b] = betas[b*10 + lane];
    if (lane == 0) PFt[217*B_N + b] = 1.f;

    if (lane == 0) {
        #pragma unroll
        for (int r = 0; r < 3; ++r) {
            sG[0][r*4+0] = sR[0][r*3+0];
            sG[0][r*4+1] = sR[0][r*3+1];
            sG[0][r*4+2] = sR[0][r*3+2];
            sG[0][r*4+3] = sJ[0][r];
        }
        for (int i = 1; i < 24; ++i) {
            int p = c_par[i];
            float rel0 = sJ[i][0]-sJ[p][0], rel1 = sJ[i][1]-sJ[p][1], rel2 = sJ[i][2]-sJ[p][2];
            for (int r = 0; r < 3; ++r) {
                float g0 = sG[p][r*4+0], g1 = sG[p][r*4+1], g2 = sG[p][r*4+2], g3 = sG[p][r*4+3];
                sG[i][r*4+0] = g0*sR[i][0] + g1*sR[i][3] + g2*sR[i][6];
                sG[i][r*4+1] = g0*sR[i][1] + g1*sR[i][4] + g2*sR[i][7];
                sG[i][r*4+2] = g0*sR[i][2] + g1*sR[i][5] + g2*sR[i][8];
                sG[i][r*4+3] = g0*rel0 + g1*rel1 + g2*rel2 + g3;
            }
        }
    }
    __syncthreads();
    if (lane < 24) {
        int i = lane;
        #pragma unroll
        for (int r = 0; r < 3; ++r) {
            float g0 = sG[i][r*4+0], g1 = sG[i][r*4+1], g2 = sG[i][r*4+2], g3 = sG[i][r*4+3];
            outJ[b*72 + i*3 + r] = g3;
            float t = g3 - (g0*sJ[i][0] + g1*sJ[i][1] + g2*sJ[i][2]);
            A[(b*24+i)*12 + r*4+0] = g0;
            A[(b*24+i)*12 + r*4+1] = g1;
            A[(b*24+i)*12 + r*4+2] = g2;
            A[(b*24+i)*12 + r*4+3] = t;
        }
    }
}

// ---------------- stage 2: fused v_posed GEMM + skinning (128v x 16b rebalance) ----------------
// 1-D grid 864 = 8 XCD x 108 (54 vert-tiles x 16 batch-tiles). Tile: 128 verts x 16 batches.
// Thread = (2 verts: lane & lane+64, 4 batches = wave*4+q). Per K-row: 2 global float3 +
// ONE broadcast 16B PF read + 12 pk_fma -> K-loop LDS-port demand halved vs r16.
__global__ __launch_bounds__(256, 2) void k_fused(
        const float* __restrict__ posedirs, const float* __restrict__ EXT,
        const float* __restrict__ PFt, const float* __restrict__ A,
        const float* __restrict__ W, float* __restrict__ out)
{
    constexpr int BT = 16;
    __shared__ __align__(16) float smem[16*288];   // 18432 B >= KE*BT (13952 B)

    int tid  = threadIdx.x;
    int wave = tid >> 6, lane = tid & 63;

    int bid = blockIdx.x;
    int w   = (bid & 7)*108 + (bid >> 3);
    int vt  = w >> 4, bt = w & 15;        // 54 vert-tiles x 16 batch-tiles
    int v0 = vt * 128;
    int b0 = bt * BT;
    int va = v0 + lane;                   // vert 1
    int vb = v0 + 64 + lane;              // vert 2

    int cola = (va < V_N) ? va*3 : v0*3;
    int colb = (vb < V_N) ? vb*3 : v0*3;

    // stage PF^T [KE][16]
    #pragma unroll 1
    for (int idx = tid; idx < KE*BT; idx += 256) {
        int r = idx >> 4, bl = idx & 15;
        smem[r*BT + bl] = PFt[r*B_N + b0 + bl];
    }
    __syncthreads();

    // named packed accumulators (batch pairs p=0: b(0,1), p=1: b(2,3)) per vert
    v2f a1x[2], a1y[2], a1z[2], a2x[2], a2y[2], a2z[2];
    #pragma unroll
    for (int p = 0; p < 2; ++p) {
        a1x[p] = (v2f){0.f,0.f}; a1y[p] = (v2f){0.f,0.f}; a1z[p] = (v2f){0.f,0.f};
        a2x[p] = (v2f){0.f,0.f}; a2y[p] = (v2f){0.f,0.f}; a2z[p] = (v2f){0.f,0.f};
    }

    int pfb = wave*4;

#define ROW_BODY                                                                  \
    {                                                                             \
        float x1 = p1[0], y1 = p1[1], z1 = p1[2];                                 \
        float x2 = p2[0], y2 = p2[1], z2 = p2[2];                                 \
        const v2f* pfp = reinterpret_cast<const v2f*>(&smem[r*BT + pfb]);         \
        v2f pf01 = pfp[0], pf23 = pfp[1];                                         \
        a1x[0] = __builtin_elementwise_fma(pf01, (v2f){x1,x1}, a1x[0]);           \
        a1x[1] = __builtin_elementwise_fma(pf23, (v2f){x1,x1}, a1x[1]);           \
        a1y[0] = __builtin_elementwise_fma(pf01, (v2f){y1,y1}, a1y[0]);           \
        a1y[1] = __builtin_elementwise_fma(pf23, (v2f){y1,y1}, a1y[1]);           \
        a1z[0] = __builtin_elementwise_fma(pf01, (v2f){z1,z1}, a1z[0]);           \
        a1z[1] = __builtin_elementwise_fma(pf23, (v2f){z1,z1}, a1z[1]);           \
        a2x[0] = __builtin_elementwise_fma(pf01, (v2f){x2,x2}, a2x[0]);           \
        a2x[1] = __builtin_elementwise_fma(pf23, (v2f){x2,x2}, a2x[1]);           \
        a2y[0] = __builtin_elementwise_fma(pf01, (v2f){y2,y2}, a2y[0]);           \
        a2y[1] = __builtin_elementwise_fma(pf23, (v2f){y2,y2}, a2y[1]);           \
        a2z[0] = __builtin_elementwise_fma(pf01, (v2f){z2,z2}, a2z[0]);           \
        a2z[1] = __builtin_elementwise_fma(pf23, (v2f){z2,z2}, a2z[1]);           \
    }

    {
        const float* p1 = posedirs + cola;
        const float* p2 = posedirs + colb;
        #pragma unroll 8
        for (int r = 0; r < KPF; ++r) {
            ROW_BODY
            p1 += NCOL; p2 += NCOL;
        }
    }
    {
        const float* p1 = EXT + cola;
        const float* p2 = EXT + colb;
        #pragma unroll
        for (int r = KPF; r < KE; ++r) {
            ROW_BODY
            p1 += NCOL; p2 += NCOL;
        }
    }
#undef ROW_BODY

    __syncthreads();   // all PF reads done before overwriting smem

    // stage A (16 batches x 288 floats)
    {
        const float* Ag = A + (size_t)b0*288;
        #pragma unroll 1
        for (int idx = tid; idx < BT*288; idx += 256)
            smem[idx] = Ag[idx];
    }
    __syncthreads();

    // ---- epilogue vert 1 ----
    {
        int vc = (va < V_N) ? va : (V_N - 1);
        const float4* W4 = reinterpret_cast<const float4*>(W + (size_t)vc*24);
        float4 w0 = W4[0], w1 = W4[1], w2 = W4[2], w3 = W4[3], w4 = W4[4], w5 = W4[5];
        float wv[24] = {w0.x,w0.y,w0.z,w0.w, w1.x,w1.y,w1.z,w1.w, w2.x,w2.y,w2.z,w2.w,
                        w3.x,w3.y,w3.z,w3.w, w4.x,w4.y,w4.z,w4.w, w5.x,w5.y,w5.z,w5.w};
        #pragma unroll
        for (int q = 0; q < 4; ++q) {
            int bb = wave*4 + q;
            const float* Ab = smem + bb*288;
            v2f T01 = {0.f,0.f}, T23 = {0.f,0.f}, T45 = {0.f,0.f};
            v2f T67 = {0.f,0.f}, T89 = {0.f,0.f}, Tab = {0.f,0.f};
            #pragma unroll
            for (int j = 0; j < 24; ++j) {
                float ww = wv[j];
                v2f wwv = {ww, ww};
                float4 q0 = *reinterpret_cast<const float4*>(Ab + j*12 + 0);
                float4 q1 = *reinterpret_cast<const float4*>(Ab + j*12 + 4);
                float4 q2 = *reinterpret_cast<const float4*>(Ab + j*12 + 8);
                T01 = __builtin_elementwise_fma(wwv, (v2f){q0.x,q0.y}, T01);
                T23 = __builtin_elementwise_fma(wwv, (v2f){q0.z,q0.w}, T23);
                T45 = __builtin_elementwise_fma(wwv, (v2f){q1.x,q1.y}, T45);
                T67 = __builtin_elementwise_fma(wwv, (v2f){q1.z,q1.w}, T67);
                T89 = __builtin_elementwise_fma(wwv, (v2f){q2.x,q2.y}, T89);
                Tab = __builtin_elementwise_fma(wwv, (v2f){q2.z,q2.w}, Tab);
            }
            if (va < V_N) {
                int pp = q >> 1;
                float x = (q & 1) ? a1x[pp].y : a1x[pp].x;
                float y = (q & 1) ? a1y[pp].y : a1y[pp].x;
                float z = (q & 1) ? a1z[pp].y : a1z[pp].x;
                size_t o = (size_t)(b0 + bb)*NCOL + (size_t)va*3;
                out[o+0] = T01.x*x + T01.y*y + T23.x*z + T23.y;
                out[o+1] = T45.x*x + T45.y*y + T67.x*z + T67.y;
                out[o+2] = T89.x*x + T89.y*y + Tab.x*z + Tab.y;
            }
        }
    }
    // ---- epilogue vert 2 ----
    {
        int vc = (vb < V_N) ? vb : (V_N - 1);
        const float4* W4 = reinterpret_cast<const float4*>(W + (size_t)vc*24);
        float4 w0 = W4[0], w1 = W4[1], w2 = W4[2], w3 = W4[3], w4 = W4[4], w5 = W4[5];
        float wv[24] = {w0.x,w0.y,w0.z,w0.w, w1.x,w1.y,w1.z,w1.w, w2.x,w2.y,w2.z,w2.w,
                        w3.x,w3.y,w3.z,w3.w, w4.x,w4.y,w4.z,w4.w, w5.x,w5.y,w5.z,w5.w};
        #pragma unroll
        for (int q = 0; q < 4; ++q) {
            int bb = wave*4 + q;
            const float* Ab = smem + bb*288;
            v2f T01 = {0.f,0.f}, T23 = {0.f,0.f}, T45 = {0.f,0.f};
            v2f T67 = {0.f,0.f}, T89 = {0.f,0.f}, Tab = {0.f,0.f};
            #pragma unroll
            for (int j = 0; j < 24; ++j) {
                float ww = wv[j];
                v2f wwv = {ww, ww};
                float4 q0 = *reinterpret_cast<const float4*>(Ab + j*12 + 0);
                float4 q1 = *reinterpret_cast<const float4*>(Ab + j*12 + 4);
                float4 q2 = *reinterpret_cast<const float4*>(Ab + j*12 + 8);
                T01 = __builtin_elementwise_fma(wwv, (v2f){q0.x,q0.y}, T01);
                T23 = __builtin_elementwise_fma(wwv, (v2f){q0.z,q0.w}, T23);
                T45 = __builtin_elementwise_fma(wwv, (v2f){q1.x,q1.y}, T45);
                T67 = __builtin_elementwise_fma(wwv, (v2f){q1.z,q1.w}, T67);
                T89 = __builtin_elementwise_fma(wwv, (v2f){q2.x,q2.y}, T89);
                Tab = __builtin_elementwise_fma(wwv, (v2f){q2.z,q2.w}, Tab);
            }
            if (vb < V_N) {
                int pp = q >> 1;
                float x = (q & 1) ? a2x[pp].y : a2x[pp].x;
                float y = (q & 1) ? a2y[pp].y : a2y[pp].x;
                float z = (q & 1) ? a2z[pp].y : a2z[pp].x;
                size_t o = (size_t)(b0 + bb)*NCOL + (size_t)vb*3;
                out[o+0] = T01.x*x + T01.y*y + T23.x*z + T23.y;
                out[o+1] = T45.x*x + T45.y*y + T67.x*z + T67.y;
                out[o+2] = T89.x*x + T89.y*y + Tab.x*z + Tab.y;
            }
        }
    }
}

extern "C" void kernel_launch(void* const* d_in, const int* in_sizes, int n_in,
                              void* d_out, int out_size, void* d_ws, size_t ws_size,
                              hipStream_t stream)
{
    const float* betas      = (const float*)d_in[0];
    const float* pose       = (const float*)d_in[1];
    const float* v_template = (const float*)d_in[2];
    const float* shapedirs  = (const float*)d_in[3];
    const float* posedirs   = (const float*)d_in[4];
    const float* Jreg       = (const float*)d_in[5];
    const float* lbs        = (const float*)d_in[6];

    float* ws   = (float*)d_ws;
    float* PFt  = ws + WS_PF;
    float* A    = ws + WS_A;
    float* EXT  = ws + WS_EXT;
    float* part = ws + WS_PART;

    float* verts = (float*)d_out;
    float* outJ  = verts + (size_t)B_N*V_N*3;

    hipLaunchKernelGGL(k_pre, dim3(96 + 81), dim3(256), 0, stream, Jreg, v_template, shapedirs, part, EXT);
    hipLaunchKernelGGL(k_batch, dim3(256), dim3(64), 0, stream, pose, betas, part, PFt, A, outJ);
    hipLaunchKernelGGL(k_fused, dim3(8*108), dim3(256), 0, stream, posedirs, EXT, PFt, A, lbs, verts);
}

// Round 20
// 83.682 us; speedup vs baseline: 1.4021x; 1.4021x over previous
//
#include <hip/hip_runtime.h>
#include <math.h>

#define B_N 256
#define V_N 6890
#define J_N 24
#define KPF 207
#define KE  218
#define NCOL (V_N*3)   // 20670

typedef float v2f __attribute__((ext_vector_type(2)));

__device__ __constant__ int c_par[24] = {-1,0,0,0,1,2,3,4,5,6,7,8,9,9,9,12,13,14,16,17,18,19,20,21};

// ws layout (floats)
#define WS_PF   0
#define WS_A    (WS_PF + B_N*KE)                 // 55808 (PF stored transposed [KE][B_N])
#define WS_EXT  (WS_A + B_N*J_N*12)              // 129536
#define WS_PART (WS_EXT + 11*NCOL)               // 356906 (96*33 = 3168)

// ---------------- stage 0: merged {joint-regressor partials | EXT build} ----------------
__global__ __launch_bounds__(256) void k_pre(const float* __restrict__ Jreg,
        const float* __restrict__ vt, const float* __restrict__ sd,
        float* __restrict__ part, float* __restrict__ EXT)
{
    int bid = blockIdx.x;
    int tid = threadIdx.x;
    __shared__ float red[4][33];

    if (bid < 96) {
        int j = bid >> 2;
        int c = bid & 3;
        int v0 = c * 1723;
        int v1 = v0 + 1723; if (v1 > V_N) v1 = V_N;

        float acc[33];
        #pragma unroll
        for (int i = 0; i < 33; ++i) acc[i] = 0.f;

        for (int v = v0 + tid; v < v1; v += 256) {
            float r = Jreg[j*V_N + v];
            const float* s = sd + v*30;
            #pragma unroll
            for (int i = 0; i < 30; ++i) acc[i] += r * s[i];
            #pragma unroll
            for (int k = 0; k < 3; ++k) acc[30+k] += r * vt[v*3+k];
        }
        #pragma unroll
        for (int i = 0; i < 33; ++i) {
            #pragma unroll
            for (int off = 32; off > 0; off >>= 1)
                acc[i] += __shfl_down(acc[i], off, 64);
        }
        int wave = tid >> 6, lane = tid & 63;
        if (lane == 0) {
            #pragma unroll
            for (int i = 0; i < 33; ++i) red[wave][i] = acc[i];
        }
        __syncthreads();
        if (tid < 33) {
            float s = red[0][tid] + red[1][tid] + red[2][tid] + red[3][tid];
            part[(j*4 + c)*33 + tid] = s;
        }
    } else {
        int idx = (bid - 96)*256 + tid;
        if (idx < NCOL) {
            int v = idx / 3, k = idx - v*3;
            #pragma unroll
            for (int l = 0; l < 10; ++l) EXT[l*NCOL + idx] = sd[v*30 + k*10 + l];
            EXT[10*NCOL + idx] = vt[idx];
        }
    }
}

// ---------------- stage 1: per-batch Rodrigues + kinematic chain (+ folded jred) ----------------
// PF is written TRANSPOSED: PFt[r*B_N + b]
__global__ __launch_bounds__(64) void k_batch(const float* __restrict__ pose,
        const float* __restrict__ betas, const float* __restrict__ part,
        float* __restrict__ PFt, float* __restrict__ A, float* __restrict__ outJ)
{
    int b = blockIdx.x;
    int lane = threadIdx.x;
    __shared__ float sR[24][9];
    __shared__ float sJ[24][3];
    __shared__ float sG[24][12];

    if (lane < 24) {
        float R[9];
        if (lane < 22) {
            float p0 = pose[b*72 + lane*3 + 0];
            float p1 = pose[b*72 + lane*3 + 1];
            float p2 = pose[b*72 + lane*3 + 2];
            float a0 = p0 + 1e-8f, a1 = p1 + 1e-8f, a2 = p2 + 1e-8f;
            float angle = sqrtf(a0*a0 + a1*a1 + a2*a2);
            float inv = 1.f / angle;
            float rx = p0*inv, ry = p1*inv, rz = p2*inv;
            float cc = cosf(angle), ss = sinf(angle), ic = 1.f - cc;
            R[0] = 1.f - ic*(ry*ry + rz*rz);
            R[1] = -ss*rz + ic*rx*ry;
            R[2] =  ss*ry + ic*rx*rz;
            R[3] =  ss*rz + ic*rx*ry;
            R[4] = 1.f - ic*(rx*rx + rz*rz);
            R[5] = -ss*rx + ic*ry*rz;
            R[6] = -ss*ry + ic*rx*rz;
            R[7] =  ss*rx + ic*ry*rz;
            R[8] = 1.f - ic*(rx*rx + ry*ry);
        } else {
            R[0]=1.f;R[1]=0.f;R[2]=0.f;R[3]=0.f;R[4]=1.f;R[5]=0.f;R[6]=0.f;R[7]=0.f;R[8]=1.f;
        }
        #pragma unroll
        for (int e = 0; e < 9; ++e) sR[lane][e] = R[e];
    }
    __syncthreads();
    for (int idx = lane; idx < 72; idx += 64) {
        int j = idx / 3, k = idx - j*3;
        const float* p0 = part + (j*4 + 0)*33;
        const float* p1 = part + (j*4 + 1)*33;
        const float* p2 = part + (j*4 + 2)*33;
        const float* p3 = part + (j*4 + 3)*33;
        float s = p0[30+k] + p1[30+k] + p2[30+k] + p3[30+k];
        #pragma unroll
        for (int l = 0; l < 10; ++l) {
            float js = p0[k*10+l] + p1[k*10+l] + p2[k*10+l] + p3[k*10+l];
            s += betas[b*10+l] * js;
        }
        sJ[j][k] = s;
    }
    __syncthreads();
    for (int idx = lane; idx < KPF; idx += 64) {
        int jj = 1 + idx/9, e = idx - (idx/9)*9;
        float id = (e==0 || e==4 || e==8) ? 1.f : 0.f;
        PFt[idx*B_N + b] = sR[jj][e] - id;
    }
    if (lane < 10) PFt[(KPF+lane)*B_N + b] = betas[b*10 + lane];
    if (lane == 0) PFt[217*B_N + b] = 1.f;

    if (lane == 0) {
        #pragma unroll
        for (int r = 0; r < 3; ++r) {
            sG[0][r*4+0] = sR[0][r*3+0];
            sG[0][r*4+1] = sR[0][r*3+1];
            sG[0][r*4+2] = sR[0][r*3+2];
            sG[0][r*4+3] = sJ[0][r];
        }
        for (int i = 1; i < 24; ++i) {
            int p = c_par[i];
            float rel0 = sJ[i][0]-sJ[p][0], rel1 = sJ[i][1]-sJ[p][1], rel2 = sJ[i][2]-sJ[p][2];
            for (int r = 0; r < 3; ++r) {
                float g0 = sG[p][r*4+0], g1 = sG[p][r*4+1], g2 = sG[p][r*4+2], g3 = sG[p][r*4+3];
                sG[i][r*4+0] = g0*sR[i][0] + g1*sR[i][3] + g2*sR[i][6];
                sG[i][r*4+1] = g0*sR[i][1] + g1*sR[i][4] + g2*sR[i][7];
                sG[i][r*4+2] = g0*sR[i][2] + g1*sR[i][5] + g2*sR[i][8];
                sG[i][r*4+3] = g0*rel0 + g1*rel1 + g2*rel2 + g3;
            }
        }
    }
    __syncthreads();
    if (lane < 24) {
        int i = lane;
        #pragma unroll
        for (int r = 0; r < 3; ++r) {
            float g0 = sG[i][r*4+0], g1 = sG[i][r*4+1], g2 = sG[i][r*4+2], g3 = sG[i][r*4+3];
            outJ[b*72 + i*3 + r] = g3;
            float t = g3 - (g0*sJ[i][0] + g1*sJ[i][1] + g2*sJ[i][2]);
            A[(b*24+i)*12 + r*4+0] = g0;
            A[(b*24+i)*12 + r*4+1] = g1;
            A[(b*24+i)*12 + r*4+2] = g2;
            A[(b*24+i)*12 + r*4+3] = t;
        }
    }
}

// ---------------- stage 2: fused v_posed GEMM + skinning (verified best: r16/r18) ----------------
// 1-D grid 864 XCD-swizzled. Tile: 64 verts x 32 batches; thread = (vert=lane, 8 batches).
// K-loop: PF batch-pairs read directly from LDS as v2f; only x,y,z splat per row.
__global__ __launch_bounds__(256, 2) void k_fused(
        const float* __restrict__ posedirs, const float* __restrict__ EXT,
        const float* __restrict__ PFt, const float* __restrict__ A,
        const float* __restrict__ W, float* __restrict__ out)
{
    constexpr int BT = 32;
    __shared__ __align__(16) float smem[BT*288];   // 36864 B >= KE*BT (27904 B)

    int tid  = threadIdx.x;
    int wave = tid >> 6, lane = tid & 63;

    int bid = blockIdx.x;
    int w   = (bid & 7)*108 + (bid >> 3);
    int vt  = w >> 3, bt = w & 7;
    int v0 = vt * 64;
    int b0 = bt * BT;
    int v  = v0 + lane;

    int col = (v < V_N) ? v*3 : v0*3;

    // stage PF^T (coalesced reads, conflict-free writes)
    #pragma unroll 1
    for (int idx = tid; idx < KE*BT; idx += 256) {
        int r = idx >> 5, bl = idx & 31;
        smem[r*BT + bl] = PFt[r*B_N + b0 + bl];
    }
    __syncthreads();

    // batch-pair packed accumulators
    v2f accx[4], accy[4], accz[4];
    #pragma unroll
    for (int p = 0; p < 4; ++p) {
        accx[p] = (v2f){0.f,0.f}; accy[p] = (v2f){0.f,0.f}; accz[p] = (v2f){0.f,0.f};
    }

    int pfb = wave*8;

#define ROW_BODY                                                                  \
    {                                                                             \
        float x = p[0], y = p[1], z = p[2];                                       \
        const v2f* pfp = reinterpret_cast<const v2f*>(&smem[r*BT + pfb]);         \
        v2f xx = {x, x}, yy = {y, y}, zz = {z, z};                                \
        accx[0] = __builtin_elementwise_fma(pfp[0], xx, accx[0]);                 \
        accx[1] = __builtin_elementwise_fma(pfp[1], xx, accx[1]);                 \
        accx[2] = __builtin_elementwise_fma(pfp[2], xx, accx[2]);                 \
        accx[3] = __builtin_elementwise_fma(pfp[3], xx, accx[3]);                 \
        accy[0] = __builtin_elementwise_fma(pfp[0], yy, accy[0]);                 \
        accy[1] = __builtin_elementwise_fma(pfp[1], yy, accy[1]);                 \
        accy[2] = __builtin_elementwise_fma(pfp[2], yy, accy[2]);                 \
        accy[3] = __builtin_elementwise_fma(pfp[3], yy, accy[3]);                 \
        accz[0] = __builtin_elementwise_fma(pfp[0], zz, accz[0]);                 \
        accz[1] = __builtin_elementwise_fma(pfp[1], zz, accz[1]);                 \
        accz[2] = __builtin_elementwise_fma(pfp[2], zz, accz[2]);                 \
        accz[3] = __builtin_elementwise_fma(pfp[3], zz, accz[3]);                 \
    }

    {
        const float* p = posedirs + col;
        #pragma unroll 8
        for (int r = 0; r < KPF; ++r) {
            ROW_BODY
            p += NCOL;
        }
    }
    {
        const float* p = EXT + col;
        #pragma unroll
        for (int r = KPF; r < KE; ++r) {
            ROW_BODY
            p += NCOL;
        }
    }
#undef ROW_BODY

    __syncthreads();   // all PF reads done before overwriting smem

    // stage A (32 batches x 288 floats)
    {
        const float* Ag = A + (size_t)b0*288;
        #pragma unroll 1
        for (int idx = tid; idx < BT*288; idx += 256)
            smem[idx] = Ag[idx];
    }

    // per-vertex weights (16B-aligned rows; clamped index, stores masked)
    int vc = (v < V_N) ? v : (V_N - 1);
    const float4* W4 = reinterpret_cast<const float4*>(W + (size_t)vc*24);
    float4 w0 = W4[0], w1 = W4[1], w2 = W4[2], w3 = W4[3], w4 = W4[4], w5 = W4[5];
    __syncthreads();

    float wv[24] = {w0.x,w0.y,w0.z,w0.w, w1.x,w1.y,w1.z,w1.w, w2.x,w2.y,w2.z,w2.w,
                    w3.x,w3.y,w3.z,w3.w, w4.x,w4.y,w4.z,w4.w, w5.x,w5.y,w5.z,w5.w};

    // FULLY UNROLLED epilogue with packed T (6 x v2f per batch)
    #pragma unroll
    for (int k = 0; k < 8; ++k) {
        int bb = wave*8 + k;
        const float* Ab = smem + bb*288;
        v2f T01 = {0.f,0.f}, T23 = {0.f,0.f}, T45 = {0.f,0.f};
        v2f T67 = {0.f,0.f}, T89 = {0.f,0.f}, Tab = {0.f,0.f};
        #pragma unroll
        for (int j = 0; j < 24; ++j) {
            float ww = wv[j];
            v2f wwv = {ww, ww};
            float4 a0 = *reinterpret_cast<const float4*>(Ab + j*12 + 0);
            float4 a1 = *reinterpret_cast<const float4*>(Ab + j*12 + 4);
            float4 a2 = *reinterpret_cast<const float4*>(Ab + j*12 + 8);
            T01 = __builtin_elementwise_fma(wwv, (v2f){a0.x,a0.y}, T01);
            T23 = __builtin_elementwise_fma(wwv, (v2f){a0.z,a0.w}, T23);
            T45 = __builtin_elementwise_fma(wwv, (v2f){a1.x,a1.y}, T45);
            T67 = __builtin_elementwise_fma(wwv, (v2f){a1.z,a1.w}, T67);
            T89 = __builtin_elementwise_fma(wwv, (v2f){a2.x,a2.y}, T89);
            Tab = __builtin_elementwise_fma(wwv, (v2f){a2.z,a2.w}, Tab);
        }
        if (v < V_N) {
            int pp = k >> 1;
            float x = (k & 1) ? accx[pp].y : accx[pp].x;
            float y = (k & 1) ? accy[pp].y : accy[pp].x;
            float z = (k & 1) ? accz[pp].y : accz[pp].x;
            size_t o = (size_t)(b0 + bb)*NCOL + (size_t)v*3;
            out[o+0] = T01.x*x + T01.y*y + T23.x*z + T23.y;
            out[o+1] = T45.x*x + T45.y*y + T67.x*z + T67.y;
            out[o+2] = T89.x*x + T89.y*y + Tab.x*z + Tab.y;
        }
    }
}

extern "C" void kernel_launch(void* const* d_in, const int* in_sizes, int n_in,
                              void* d_out, int out_size, void* d_ws, size_t ws_size,
                              hipStream_t stream)
{
    const float* betas      = (const float*)d_in[0];
    const float* pose       = (const float*)d_in[1];
    const float* v_template = (const float*)d_in[2];
    const float* shapedirs  = (const float*)d_in[3];
    const float* posedirs   = (const float*)d_in[4];
    const float* Jreg       = (const float*)d_in[5];
    const float* lbs        = (const float*)d_in[6];

    float* ws   = (float*)d_ws;
    float* PFt  = ws + WS_PF;
    float* A    = ws + WS_A;
    float* EXT  = ws + WS_EXT;
    float* part = ws + WS_PART;

    float* verts = (float*)d_out;
    float* outJ  = verts + (size_t)B_N*V_N*3;

    hipLaunchKernelGGL(k_pre, dim3(96 + 81), dim3(256), 0, stream, Jreg, v_template, shapedirs, part, EXT);
    hipLaunchKernelGGL(k_batch, dim3(256), dim3(64), 0, stream, pose, betas, part, PFt, A, outJ);
    hipLaunchKernelGGL(k_fused, dim3(8*108), dim3(256), 0, stream, posedirs, EXT, PFt, A, lbs, verts);
}

// Round 21
// 82.977 us; speedup vs baseline: 1.4140x; 1.0085x over previous
//
#include <hip/hip_runtime.h>
#include <math.h>

#define B_N 256
#define V_N 6890
#define J_N 24
#define KPF 207
#define KE  218
#define NCOL (V_N*3)   // 20670

typedef float v2f __attribute__((ext_vector_type(2)));

__device__ __constant__ int c_par[24] = {-1,0,0,0,1,2,3,4,5,6,7,8,9,9,9,12,13,14,16,17,18,19,20,21};

// ws layout (floats)
#define WS_PF   0
#define WS_A    (WS_PF + B_N*KE)                 // 55808 (PF stored transposed [KE][B_N])
#define WS_EXT  (WS_A + B_N*J_N*12)              // 129536
#define WS_PART (WS_EXT + 11*NCOL)               // 356906 (96*33 = 3168)

// ---------------- stage 0: merged {joint-regressor partials | EXT build} ----------------
__global__ __launch_bounds__(256) void k_pre(const float* __restrict__ Jreg,
        const float* __restrict__ vt, const float* __restrict__ sd,
        float* __restrict__ part, float* __restrict__ EXT)
{
    int bid = blockIdx.x;
    int tid = threadIdx.x;
    __shared__ float red[4][33];

    if (bid < 96) {
        int j = bid >> 2;
        int c = bid & 3;
        int v0 = c * 1723;
        int v1 = v0 + 1723; if (v1 > V_N) v1 = V_N;

        float acc[33];
        #pragma unroll
        for (int i = 0; i < 33; ++i) acc[i] = 0.f;

        for (int v = v0 + tid; v < v1; v += 256) {
            float r = Jreg[j*V_N + v];
            const float* s = sd + v*30;
            #pragma unroll
            for (int i = 0; i < 30; ++i) acc[i] += r * s[i];
            #pragma unroll
            for (int k = 0; k < 3; ++k) acc[30+k] += r * vt[v*3+k];
        }
        #pragma unroll
        for (int i = 0; i < 33; ++i) {
            #pragma unroll
            for (int off = 32; off > 0; off >>= 1)
                acc[i] += __shfl_down(acc[i], off, 64);
        }
        int wave = tid >> 6, lane = tid & 63;
        if (lane == 0) {
            #pragma unroll
            for (int i = 0; i < 33; ++i) red[wave][i] = acc[i];
        }
        __syncthreads();
        if (tid < 33) {
            float s = red[0][tid] + red[1][tid] + red[2][tid] + red[3][tid];
            part[(j*4 + c)*33 + tid] = s;
        }
    } else {
        int idx = (bid - 96)*256 + tid;
        if (idx < NCOL) {
            int v = idx / 3, k = idx - v*3;
            #pragma unroll
            for (int l = 0; l < 10; ++l) EXT[l*NCOL + idx] = sd[v*30 + k*10 + l];
            EXT[10*NCOL + idx] = vt[idx];
        }
    }
}

// ---------------- stage 1: per-batch Rodrigues + kinematic chain (+ folded jred) ----------------
// PF is written TRANSPOSED: PFt[r*B_N + b]
__global__ __launch_bounds__(64) void k_batch(const float* __restrict__ pose,
        const float* __restrict__ betas, const float* __restrict__ part,
        float* __restrict__ PFt, float* __restrict__ A, float* __restrict__ outJ)
{
    int b = blockIdx.x;
    int lane = threadIdx.x;
    __shared__ float sR[24][9];
    __shared__ float sJ[24][3];
    __shared__ float sG[24][12];

    if (lane < 24) {
        float R[9];
        if (lane < 22) {
            float p0 = pose[b*72 + lane*3 + 0];
            float p1 = pose[b*72 + lane*3 + 1];
            float p2 = pose[b*72 + lane*3 + 2];
            float a0 = p0 + 1e-8f, a1 = p1 + 1e-8f, a2 = p2 + 1e-8f;
            float angle = sqrtf(a0*a0 + a1*a1 + a2*a2);
            float inv = 1.f / angle;
            float rx = p0*inv, ry = p1*inv, rz = p2*inv;
            float cc = cosf(angle), ss = sinf(angle), ic = 1.f - cc;
            R[0] = 1.f - ic*(ry*ry + rz*rz);
            R[1] = -ss*rz + ic*rx*ry;
            R[2] =  ss*ry + ic*rx*rz;
            R[3] =  ss*rz + ic*rx*ry;
            R[4] = 1.f - ic*(rx*rx + rz*rz);
            R[5] = -ss*rx + ic*ry*rz;
            R[6] = -ss*ry + ic*rx*rz;
            R[7] =  ss*rx + ic*ry*rz;
            R[8] = 1.f - ic*(rx*rx + ry*ry);
        } else {
            R[0]=1.f;R[1]=0.f;R[2]=0.f;R[3]=0.f;R[4]=1.f;R[5]=0.f;R[6]=0.f;R[7]=0.f;R[8]=1.f;
        }
        #pragma unroll
        for (int e = 0; e < 9; ++e) sR[lane][e] = R[e];
    }
    __syncthreads();
    for (int idx = lane; idx < 72; idx += 64) {
        int j = idx / 3, k = idx - j*3;
        const float* p0 = part + (j*4 + 0)*33;
        const float* p1 = part + (j*4 + 1)*33;
        const float* p2 = part + (j*4 + 2)*33;
        const float* p3 = part + (j*4 + 3)*33;
        float s = p0[30+k] + p1[30+k] + p2[30+k] + p3[30+k];
        #pragma unroll
        for (int l = 0; l < 10; ++l) {
            float js = p0[k*10+l] + p1[k*10+l] + p2[k*10+l] + p3[k*10+l];
            s += betas[b*10+l] * js;
        }
        sJ[j][k] = s;
    }
    __syncthreads();
    for (int idx = lane; idx < KPF; idx += 64) {
        int jj = 1 + idx/9, e = idx - (idx/9)*9;
        float id = (e==0 || e==4 || e==8) ? 1.f : 0.f;
        PFt[idx*B_N + b] = sR[jj][e] - id;
    }
    if (lane < 10) PFt[(KPF+lane)*B_N + b] = betas[b*10 + lane];
    if (lane == 0) PFt[217*B_N + b] = 1.f;

    if (lane == 0) {
        #pragma unroll
        for (int r = 0; r < 3; ++r) {
            sG[0][r*4+0] = sR[0][r*3+0];
            sG[0][r*4+1] = sR[0][r*3+1];
            sG[0][r*4+2] = sR[0][r*3+2];
            sG[0][r*4+3] = sJ[0][r];
        }
        for (int i = 1; i < 24; ++i) {
            int p = c_par[i];
            float rel0 = sJ[i][0]-sJ[p][0], rel1 = sJ[i][1]-sJ[p][1], rel2 = sJ[i][2]-sJ[p][2];
            for (int r = 0; r < 3; ++r) {
                float g0 = sG[p][r*4+0], g1 = sG[p][r*4+1], g2 = sG[p][r*4+2], g3 = sG[p][r*4+3];
                sG[i][r*4+0] = g0*sR[i][0] + g1*sR[i][3] + g2*sR[i][6];
                sG[i][r*4+1] = g0*sR[i][1] + g1*sR[i][4] + g2*sR[i][7];
                sG[i][r*4+2] = g0*sR[i][2] + g1*sR[i][5] + g2*sR[i][8];
                sG[i][r*4+3] = g0*rel0 + g1*rel1 + g2*rel2 + g3;
            }
        }
    }
    __syncthreads();
    if (lane < 24) {
        int i = lane;
        #pragma unroll
        for (int r = 0; r < 3; ++r) {
            float g0 = sG[i][r*4+0], g1 = sG[i][r*4+1], g2 = sG[i][r*4+2], g3 = sG[i][r*4+3];
            outJ[b*72 + i*3 + r] = g3;
            float t = g3 - (g0*sJ[i][0] + g1*sJ[i][1] + g2*sJ[i][2]);
            A[(b*24+i)*12 + r*4+0] = g0;
            A[(b*24+i)*12 + r*4+1] = g1;
            A[(b*24+i)*12 + r*4+2] = g2;
            A[(b*24+i)*12 + r*4+3] = t;
        }
    }
}

// ---------------- stage 2: fused v_posed GEMM + skinning (r18 + 2-row register pipeline) ----------------
// 1-D grid 864 XCD-swizzled. Tile: 64 verts x 32 batches; thread = (vert=lane, 8 batches).
// K-loop processes ROW PAIRS with named register staging (2x in-flight memory per wave).
__global__ __launch_bounds__(256, 2) void k_fused(
        const float* __restrict__ posedirs, const float* __restrict__ EXT,
        const float* __restrict__ PFt, const float* __restrict__ A,
        const float* __restrict__ W, float* __restrict__ out)
{
    constexpr int BT = 32;
    __shared__ __align__(16) float smem[BT*288];   // 36864 B >= KE*BT (27904 B)

    int tid  = threadIdx.x;
    int wave = tid >> 6, lane = tid & 63;

    int bid = blockIdx.x;
    int w   = (bid & 7)*108 + (bid >> 3);
    int vt  = w >> 3, bt = w & 7;
    int v0 = vt * 64;
    int b0 = bt * BT;
    int v  = v0 + lane;

    int col = (v < V_N) ? v*3 : v0*3;

    // stage PF^T (coalesced reads, conflict-free writes)
    #pragma unroll 1
    for (int idx = tid; idx < KE*BT; idx += 256) {
        int r = idx >> 5, bl = idx & 31;
        smem[r*BT + bl] = PFt[r*B_N + b0 + bl];
    }
    __syncthreads();

    // batch-pair packed accumulators
    v2f accx[4], accy[4], accz[4];
    #pragma unroll
    for (int p = 0; p < 4; ++p) {
        accx[p] = (v2f){0.f,0.f}; accy[p] = (v2f){0.f,0.f}; accz[p] = (v2f){0.f,0.f};
    }

    int pfb = wave*8;

#define FMA_ROW(Q0,Q1,Q2,Q3,X,Y,Z)                                               \
    {                                                                             \
        v2f xx = {X, X}, yy = {Y, Y}, zz = {Z, Z};                                \
        accx[0] = __builtin_elementwise_fma(Q0, xx, accx[0]);                     \
        accx[1] = __builtin_elementwise_fma(Q1, xx, accx[1]);                     \
        accx[2] = __builtin_elementwise_fma(Q2, xx, accx[2]);                     \
        accx[3] = __builtin_elementwise_fma(Q3, xx, accx[3]);                     \
        accy[0] = __builtin_elementwise_fma(Q0, yy, accy[0]);                     \
        accy[1] = __builtin_elementwise_fma(Q1, yy, accy[1]);                     \
        accy[2] = __builtin_elementwise_fma(Q2, yy, accy[2]);                     \
        accy[3] = __builtin_elementwise_fma(Q3, yy, accy[3]);                     \
        accz[0] = __builtin_elementwise_fma(Q0, zz, accz[0]);                     \
        accz[1] = __builtin_elementwise_fma(Q1, zz, accz[1]);                     \
        accz[2] = __builtin_elementwise_fma(Q2, zz, accz[2]);                     \
        accz[3] = __builtin_elementwise_fma(Q3, zz, accz[3]);                     \
    }

#define ROW_PAIR                                                                  \
    {                                                                             \
        float x0 = p[0],      y0 = p[1],        z0 = p[2];                        \
        float x1 = p[NCOL],   y1 = p[NCOL+1],   z1 = p[NCOL+2];                   \
        const v2f* pf0 = reinterpret_cast<const v2f*>(&smem[r*BT + pfb]);         \
        const v2f* pf1 = reinterpret_cast<const v2f*>(&smem[(r+1)*BT + pfb]);     \
        v2f q00 = pf0[0], q01 = pf0[1], q02 = pf0[2], q03 = pf0[3];               \
        v2f q10 = pf1[0], q11 = pf1[1], q12 = pf1[2], q13 = pf1[3];               \
        FMA_ROW(q00,q01,q02,q03, x0,y0,z0)                                        \
        FMA_ROW(q10,q11,q12,q13, x1,y1,z1)                                        \
    }

#define ROW_ONE                                                                   \
    {                                                                             \
        float x = p[0], y = p[1], z = p[2];                                       \
        const v2f* pfp = reinterpret_cast<const v2f*>(&smem[r*BT + pfb]);         \
        v2f q0 = pfp[0], q1 = pfp[1], q2 = pfp[2], q3 = pfp[3];                   \
        FMA_ROW(q0,q1,q2,q3, x,y,z)                                               \
    }

    {
        const float* p = posedirs + col;
        // rows 0..205 in pairs (103 pairs)
        #pragma unroll 4
        for (int r = 0; r < KPF-1; r += 2) {
            ROW_PAIR
            p += 2*NCOL;
        }
        // row 206
        {
            int r = KPF-1;
            ROW_ONE
        }
    }
    {
        const float* p = EXT + col;
        // rows 207..216 in pairs (5 pairs)
        #pragma unroll
        for (int r = KPF; r < KE-1; r += 2) {
            ROW_PAIR
            p += 2*NCOL;
        }
        // row 217 (p now at EXT row 10)
        {
            int r = KE-1;
            ROW_ONE
        }
    }
#undef ROW_PAIR
#undef ROW_ONE
#undef FMA_ROW

    __syncthreads();   // all PF reads done before overwriting smem

    // stage A (32 batches x 288 floats)
    {
        const float* Ag = A + (size_t)b0*288;
        #pragma unroll 1
        for (int idx = tid; idx < BT*288; idx += 256)
            smem[idx] = Ag[idx];
    }

    // per-vertex weights (16B-aligned rows; clamped index, stores masked)
    int vc = (v < V_N) ? v : (V_N - 1);
    const float4* W4 = reinterpret_cast<const float4*>(W + (size_t)vc*24);
    float4 w0 = W4[0], w1 = W4[1], w2 = W4[2], w3 = W4[3], w4 = W4[4], w5 = W4[5];
    __syncthreads();

    float wv[24] = {w0.x,w0.y,w0.z,w0.w, w1.x,w1.y,w1.z,w1.w, w2.x,w2.y,w2.z,w2.w,
                    w3.x,w3.y,w3.z,w3.w, w4.x,w4.y,w4.z,w4.w, w5.x,w5.y,w5.z,w5.w};

    // FULLY UNROLLED epilogue with packed T (6 x v2f per batch)
    #pragma unroll
    for (int k = 0; k < 8; ++k) {
        int bb = wave*8 + k;
        const float* Ab = smem + bb*288;
        v2f T01 = {0.f,0.f}, T23 = {0.f,0.f}, T45 = {0.f,0.f};
        v2f T67 = {0.f,0.f}, T89 = {0.f,0.f}, Tab = {0.f,0.f};
        #pragma unroll
        for (int j = 0; j < 24; ++j) {
            float ww = wv[j];
            v2f wwv = {ww, ww};
            float4 a0 = *reinterpret_cast<const float4*>(Ab + j*12 + 0);
            float4 a1 = *reinterpret_cast<const float4*>(Ab + j*12 + 4);
            float4 a2 = *reinterpret_cast<const float4*>(Ab + j*12 + 8);
            T01 = __builtin_elementwise_fma(wwv, (v2f){a0.x,a0.y}, T01);
            T23 = __builtin_elementwise_fma(wwv, (v2f){a0.z,a0.w}, T23);
            T45 = __builtin_elementwise_fma(wwv, (v2f){a1.x,a1.y}, T45);
            T67 = __builtin_elementwise_fma(wwv, (v2f){a1.z,a1.w}, T67);
            T89 = __builtin_elementwise_fma(wwv, (v2f){a2.x,a2.y}, T89);
            Tab = __builtin_elementwise_fma(wwv, (v2f){a2.z,a2.w}, Tab);
        }
        if (v < V_N) {
            int pp = k >> 1;
            float x = (k & 1) ? accx[pp].y : accx[pp].x;
            float y = (k & 1) ? accy[pp].y : accy[pp].x;
            float z = (k & 1) ? accz[pp].y : accz[pp].x;
            size_t o = (size_t)(b0 + bb)*NCOL + (size_t)v*3;
            out[o+0] = T01.x*x + T01.y*y + T23.x*z + T23.y;
            out[o+1] = T45.x*x + T45.y*y + T67.x*z + T67.y;
            out[o+2] = T89.x*x + T89.y*y + Tab.x*z + Tab.y;
        }
    }
}

extern "C" void kernel_launch(void* const* d_in, const int* in_sizes, int n_in,
                              void* d_out, int out_size, void* d_ws, size_t ws_size,
                              hipStream_t stream)
{
    const float* betas      = (const float*)d_in[0];
    const float* pose       = (const float*)d_in[1];
    const float* v_template = (const float*)d_in[2];
    const float* shapedirs  = (const float*)d_in[3];
    const float* posedirs   = (const float*)d_in[4];
    const float* Jreg       = (const float*)d_in[5];
    const float* lbs        = (const float*)d_in[6];

    float* ws   = (float*)d_ws;
    float* PFt  = ws + WS_PF;
    float* A    = ws + WS_A;
    float* EXT  = ws + WS_EXT;
    float* part = ws + WS_PART;

    float* verts = (float*)d_out;
    float* outJ  = verts + (size_t)B_N*V_N*3;

    hipLaunchKernelGGL(k_pre, dim3(96 + 81), dim3(256), 0, stream, Jreg, v_template, shapedirs, part, EXT);
    hipLaunchKernelGGL(k_batch, dim3(256), dim3(64), 0, stream, pose, betas, part, PFt, A, outJ);
    hipLaunchKernelGGL(k_fused, dim3(8*108), dim3(256), 0, stream, posedirs, EXT, PFt, A, lbs, verts);
}